// Round 12
// baseline (183.962 us; speedup 1.0000x reference)
//
#include <hip/hip_runtime.h>
#include <hip/hip_bf16.h>

typedef __bf16 bf16x8 __attribute__((ext_vector_type(8)));
typedef float f32x4 __attribute__((ext_vector_type(4)));
typedef float f32x16 __attribute__((ext_vector_type(16)));

__device__ inline unsigned short f2bf(float f) {
    __hip_bfloat16 h = __float2bfloat16(f);
    return __builtin_bit_cast(unsigned short, h);
}
__device__ inline unsigned pk2bf(float a, float b) {
    return (unsigned)f2bf(a) | ((unsigned)f2bf(b) << 16);
}
__device__ inline float exp2_fast(float x) {
    float r;
    asm("v_exp_f32 %0, %1" : "=v"(r) : "v"(x));
    return r;
}

#define QSCALE 0.1803368801111244f  /* 0.125 * log2(e) */

// ---------------- V transpose: x[b][n][hc+d] (f32) -> Vt[b*8+h][d][n'] (bf16) --------
// n' = column-permuted n (swap bit2<->bit3 within each 16-block) so the PV MFMA
// fragment's 8 elements are contiguous 16 bytes (single 16B load).
__global__ __launch_bounds__(256) void xpose_v(const float* __restrict__ x,
                                               unsigned short* __restrict__ Vt) {
    const int tid = threadIdx.x;
    const int lane = tid & 63, w = tid >> 6;
    const int b = blockIdx.z, h = blockIdx.y;
    const int n = blockIdx.x * 256 + w * 64 + lane;
    const int np = (n & ~15) | (n & 3) | ((n & 4) << 1) | ((n & 8) >> 1);
    const size_t xrow = ((size_t)b * 2048 + n) * 512 + h * 64;
    const size_t vbase = ((size_t)(b * 8 + h) * 64) * 2048 + np;
#pragma unroll
    for (int d0 = 0; d0 < 64; d0 += 4) {
        float4 v = *reinterpret_cast<const float4*>(&x[xrow + d0]);
        Vt[vbase + (size_t)(d0 + 0) * 2048] = f2bf(v.x);
        Vt[vbase + (size_t)(d0 + 1) * 2048] = f2bf(v.y);
        Vt[vbase + (size_t)(d0 + 2) * 2048] = f2bf(v.z);
        Vt[vbase + (size_t)(d0 + 3) * 2048] = f2bf(v.w);
    }
}

// ---------------- fused Q/K projection: C = x(8192x512) * W^T, f32 in, bf16 out ------
__global__ __launch_bounds__(256) void gemm_qk(const float* __restrict__ x,
                                               const float* __restrict__ Wq,
                                               const float* __restrict__ Wk,
                                               unsigned short* __restrict__ Qb,
                                               unsigned short* __restrict__ Kb) {
    __shared__ __align__(16) unsigned short sA[128 * 40];
    __shared__ __align__(16) unsigned short sB[128 * 40];
    const int tid  = threadIdx.x;
    const int lane = tid & 63;
    const int wave = tid >> 6;
    const int wr = wave >> 1, wc = wave & 1;
    const int bm = blockIdx.x * 128;
    const int by = blockIdx.y;
    const float* __restrict__ Bsrc = (by < 4) ? Wq : Wk;
    unsigned short* __restrict__ C = (by < 4) ? Qb : Kb;
    const int bn = (by & 3) * 128;
    const float scale = (by < 4) ? QSCALE : 1.0f;
    const int tr = tid >> 1, th = (tid & 1) * 16;
    const int rl = lane & 15;
    const int kq = (lane >> 4) * 8;

    f32x4 acc[4][4];
#pragma unroll
    for (int m = 0; m < 4; ++m)
#pragma unroll
        for (int n = 0; n < 4; ++n) acc[m][n] = (f32x4){0.f, 0.f, 0.f, 0.f};

    for (int k0 = 0; k0 < 512; k0 += 32) {
        const float* ap = &x[(size_t)(bm + tr) * 512 + k0 + th];
        const float* bp = &Bsrc[(size_t)(bn + tr) * 512 + k0 + th];
        float4 a0 = *reinterpret_cast<const float4*>(ap);
        float4 a1 = *reinterpret_cast<const float4*>(ap + 4);
        float4 a2 = *reinterpret_cast<const float4*>(ap + 8);
        float4 a3 = *reinterpret_cast<const float4*>(ap + 12);
        float4 b0 = *reinterpret_cast<const float4*>(bp);
        float4 b1 = *reinterpret_cast<const float4*>(bp + 4);
        float4 b2 = *reinterpret_cast<const float4*>(bp + 8);
        float4 b3 = *reinterpret_cast<const float4*>(bp + 12);
        uint4 pa0 = {pk2bf(a0.x, a0.y), pk2bf(a0.z, a0.w), pk2bf(a1.x, a1.y), pk2bf(a1.z, a1.w)};
        uint4 pa1 = {pk2bf(a2.x, a2.y), pk2bf(a2.z, a2.w), pk2bf(a3.x, a3.y), pk2bf(a3.z, a3.w)};
        uint4 pb0 = {pk2bf(b0.x, b0.y), pk2bf(b0.z, b0.w), pk2bf(b1.x, b1.y), pk2bf(b1.z, b1.w)};
        uint4 pb1 = {pk2bf(b2.x, b2.y), pk2bf(b2.z, b2.w), pk2bf(b3.x, b3.y), pk2bf(b3.z, b3.w)};
        __syncthreads();
        *reinterpret_cast<uint4*>(&sA[tr * 40 + th])     = pa0;
        *reinterpret_cast<uint4*>(&sA[tr * 40 + th + 8]) = pa1;
        *reinterpret_cast<uint4*>(&sB[tr * 40 + th])     = pb0;
        *reinterpret_cast<uint4*>(&sB[tr * 40 + th + 8]) = pb1;
        __syncthreads();

        bf16x8 af[4], bfv[4];
#pragma unroll
        for (int m = 0; m < 4; ++m)
            af[m] = __builtin_bit_cast(bf16x8,
                *reinterpret_cast<const uint4*>(&sA[(wr * 64 + m * 16 + rl) * 40 + kq]));
#pragma unroll
        for (int n = 0; n < 4; ++n)
            bfv[n] = __builtin_bit_cast(bf16x8,
                *reinterpret_cast<const uint4*>(&sB[(wc * 64 + n * 16 + rl) * 40 + kq]));
#pragma unroll
        for (int m = 0; m < 4; ++m)
#pragma unroll
            for (int n = 0; n < 4; ++n)
                acc[m][n] = __builtin_amdgcn_mfma_f32_16x16x32_bf16(af[m], bfv[n], acc[m][n], 0, 0, 0);
    }

    const int rq = (lane >> 4) * 4;
#pragma unroll
    for (int m = 0; m < 4; ++m) {
        int r = bm + wr * 64 + m * 16 + rq;
#pragma unroll
        for (int n = 0; n < 4; ++n) {
            int c = bn + wc * 64 + n * 16 + rl;
#pragma unroll
            for (int reg = 0; reg < 4; ++reg)
                C[(size_t)(r + reg) * 512 + c] = f2bf(acc[m][n][reg] * scale);
        }
    }
}

// ---------------- fused flash attention: NO K/V LDS staging (L2-resident K/V) --------
// grid: 1024 flat blocks (XCD bh-affinity: xcd=flat&7 owns bh {4xcd..4xcd+3}).
// block: 256 = 4 waves = 2qh x 2jp; q-tile 64, wave q-sub-tile 32; jp = 32-j parity.
// Per wave: fully independent j-loop, K/V MFMA fragments loaded DIRECTLY from global
// (L1/L2-hit; K prefetched 1 tile ahead in regs, V loaded at tile top). Positions as
// an 8KB LDS table of slopeL*pos (broadcast reads). No barriers in the main loop.
// Fragment maps identical to verified round-9 kernel:
//   S^T = mfma(K,Q): lane q=l31, j=(r&3)+8*(r>>2)+4*hi; operand elem c=16ks+8hi+e.
//   PV = mfma(V',P): P lane-local j-map 16ks+4hi+(e&3)+8*(e>>2); V' pre-permuted.
__global__ __launch_bounds__(256, 4) void attn_fwd(const unsigned short* __restrict__ Q,
                                                   const unsigned short* __restrict__ Kb,
                                                   const unsigned short* __restrict__ Vt,
                                                   const float* __restrict__ pos,
                                                   float* __restrict__ Out) {
    __shared__ __align__(16) unsigned char smem[16896];
    float* sPos = (float*)smem;   // loop phase: 2048 f32 (slopeL*pos); epilogue aliases

    const int tid  = threadIdx.x;
    const int lane = tid & 63;
    const int w    = tid >> 6;
    const int l31  = lane & 31;
    const int hi   = lane >> 5;
    const int qh   = w & 1;
    const int jp   = w >> 1;
    const int flat = blockIdx.x;
    const int xcd  = flat & 7;
    const int idx  = flat >> 3;          // 0..127
    const int bh   = xcd * 4 + (idx >> 5);
    const int qt   = idx & 31;
    const int b = bh >> 3, h = bh & 7;
    const int q0 = qt * 64 + qh * 32;
    const size_t rowbase = (size_t)b * 2048;
    const int hc = h * 64;
    const float slopeL = ldexpf(1.4426950408889634f, -(h + 1));  // slope * log2(e)

    // Q B-fragments (Q pre-scaled by 0.125*log2e)
    bf16x8 qf0, qf1, qf2, qf3;
    {
        const unsigned short* qp = &Q[(rowbase + q0 + l31) * 512 + hc + hi * 8];
        qf0 = __builtin_bit_cast(bf16x8, *reinterpret_cast<const uint4*>(qp));
        qf1 = __builtin_bit_cast(bf16x8, *reinterpret_cast<const uint4*>(qp + 16));
        qf2 = __builtin_bit_cast(bf16x8, *reinterpret_cast<const uint4*>(qp + 32));
        qf3 = __builtin_bit_cast(bf16x8, *reinterpret_cast<const uint4*>(qp + 48));
    }
    const float ui = slopeL * pos[rowbase + q0 + l31];

    // slopeL*pos table (one-time, vectorized)
    {
        f32x4* sp4 = (f32x4*)sPos;
        const float4* gp4 = (const float4*)(pos + rowbase);
#pragma unroll
        for (int i = 0; i < 2; ++i) {
            float4 v = gp4[tid + 256 * i];
            sp4[tid + 256 * i] = (f32x4){v.x * slopeL, v.y * slopeL, v.z * slopeL, v.w * slopeL};
        }
    }
    __syncthreads();

    float lloc = 0.f;
    f32x16 o0, o1;
#pragma unroll
    for (int r = 0; r < 16; ++r) { o0[r] = 0.f; o1[r] = 0.f; }

    // direct-global fragment bases
    const unsigned short* Kbase  = &Kb[(rowbase + 32 * jp + l31) * 512 + hc + hi * 8];
    const unsigned short* Vbase0 = &Vt[((size_t)bh * 64 + l31) * 2048 + 32 * jp + 8 * hi];
    const unsigned short* Vbase1 = Vbase0 + (size_t)32 * 2048;

    auto loadK = [&](int t, uint4& k0, uint4& k1, uint4& k2, uint4& k3) {
        const unsigned short* kp = Kbase + (size_t)t * 64 * 512;
        k0 = *reinterpret_cast<const uint4*>(kp);
        k1 = *reinterpret_cast<const uint4*>(kp + 16);
        k2 = *reinterpret_cast<const uint4*>(kp + 32);
        k3 = *reinterpret_cast<const uint4*>(kp + 48);
    };

    auto tile = [&](int t, uint4 k0, uint4 k1, uint4 k2, uint4 k3) {
        const int j0 = 64 * t + 32 * jp;
        // V fragment loads (hidden under QK + softmax)
        const unsigned short* vp0 = Vbase0 + t * 64;
        const unsigned short* vp1 = Vbase1 + t * 64;
        uint4 v00 = *reinterpret_cast<const uint4*>(vp0);
        uint4 v01 = *reinterpret_cast<const uint4*>(vp0 + 16);
        uint4 v10 = *reinterpret_cast<const uint4*>(vp1);
        uint4 v11 = *reinterpret_cast<const uint4*>(vp1 + 16);

        // ---- S chunk (32j x 32q) ----
        f32x16 s;
#pragma unroll
        for (int r = 0; r < 16; ++r) s[r] = 0.f;
        __builtin_amdgcn_s_setprio(1);
        s = __builtin_amdgcn_mfma_f32_32x32x16_bf16(__builtin_bit_cast(bf16x8, k0), qf0, s, 0, 0, 0);
        s = __builtin_amdgcn_mfma_f32_32x32x16_bf16(__builtin_bit_cast(bf16x8, k1), qf1, s, 0, 0, 0);
        s = __builtin_amdgcn_mfma_f32_32x32x16_bf16(__builtin_bit_cast(bf16x8, k2), qf2, s, 0, 0, 0);
        s = __builtin_amdgcn_mfma_f32_32x32x16_bf16(__builtin_bit_cast(bf16x8, k3), qf3, s, 0, 0, 0);
        __builtin_amdgcn_s_setprio(0);

        // ---- bias + exp2 (fixed reference, log2 domain) ----
        float ls = 0.f;
#pragma unroll
        for (int tt = 0; tt < 4; ++tt) {
            f32x4 u = *reinterpret_cast<const f32x4*>(&sPos[j0 + 8 * tt + 4 * hi]);
#pragma unroll
            for (int r = 0; r < 4; ++r) {
                float p = exp2_fast(s[4 * tt + r] - fabsf(u[r] - ui));
                s[4 * tt + r] = p;
                ls += p;
            }
        }
        lloc += ls;

        // ---- lane-local P fragments (j = 16ks + 4hi + (e&3) + 8*(e>>2)) ----
        bf16x8 pf0 = __builtin_bit_cast(bf16x8, (uint4){
            pk2bf(s[0], s[1]),  pk2bf(s[2], s[3]),   pk2bf(s[4], s[5]),   pk2bf(s[6], s[7])});
        bf16x8 pf1 = __builtin_bit_cast(bf16x8, (uint4){
            pk2bf(s[8], s[9]),  pk2bf(s[10], s[11]), pk2bf(s[12], s[13]), pk2bf(s[14], s[15])});

        // ---- PV: O^T[d][q] += V-frag x P-frag ----
        __builtin_amdgcn_s_setprio(1);
        o0 = __builtin_amdgcn_mfma_f32_32x32x16_bf16(__builtin_bit_cast(bf16x8, v00), pf0, o0, 0, 0, 0);
        o1 = __builtin_amdgcn_mfma_f32_32x32x16_bf16(__builtin_bit_cast(bf16x8, v10), pf0, o1, 0, 0, 0);
        o0 = __builtin_amdgcn_mfma_f32_32x32x16_bf16(__builtin_bit_cast(bf16x8, v01), pf1, o0, 0, 0, 0);
        o1 = __builtin_amdgcn_mfma_f32_32x32x16_bf16(__builtin_bit_cast(bf16x8, v11), pf1, o1, 0, 0, 0);
        __builtin_amdgcn_s_setprio(0);
    };

    // main loop: K prefetched 1 tile ahead in registers; no barriers
    uint4 a0, a1, a2, a3, c0, c1, c2, c3;
    loadK(0, a0, a1, a2, a3);
    for (int t = 0; t < 32; t += 2) {
        if (t + 1 < 32) loadK(t + 1, c0, c1, c2, c3);
        tile(t, a0, a1, a2, a3);
        if (t + 2 < 32) loadK(t + 2, a0, a1, a2, a3);
        if (t + 1 < 32) tile(t + 1, c0, c1, c2, c3);
    }

    // ---- epilogue: merge jp partials via LDS (aliases sPos), normalize, store ----
    float lt = lloc + __shfl_xor(lloc, 32, 64);  // combine hi halves (same q)
    __syncthreads();                             // everyone done with loop & sPos
    float* sMf = (float*)smem;                   // 2 qh x 32 q x 64 d = 16 KiB
    float* sMl = sMf + 4096;                     // 128 f32
    const int key = (lane & 7) << 2;
    if (jp == 1) {
        float* dst = sMf + qh * 2048 + lane * 32;
#pragma unroll
        for (int i = 0; i < 4; ++i) {
            f32x4 t0 = {o0[4 * i], o0[4 * i + 1], o0[4 * i + 2], o0[4 * i + 3]};
            f32x4 t1 = {o1[4 * i], o1[4 * i + 1], o1[4 * i + 2], o1[4 * i + 3]};
            *reinterpret_cast<f32x4*>(dst + ((4 * i) ^ key))      = t0;
            *reinterpret_cast<f32x4*>(dst + ((16 + 4 * i) ^ key)) = t1;
        }
        sMl[qh * 64 + lane] = lt;
    }
    __syncthreads();
    if (jp == 0) {
        const float* src = sMf + qh * 2048 + lane * 32;
#pragma unroll
        for (int i = 0; i < 4; ++i) {
            f32x4 t0 = *reinterpret_cast<const f32x4*>(src + ((4 * i) ^ key));
            f32x4 t1 = *reinterpret_cast<const f32x4*>(src + ((16 + 4 * i) ^ key));
#pragma unroll
            for (int r = 0; r < 4; ++r) { o0[4 * i + r] += t0[r]; o1[4 * i + r] += t1[r]; }
        }
        const float linv = 1.0f / (lt + sMl[qh * 64 + lane]);
        float* orow = &Out[(rowbase + q0 + l31) * 512 + hc];
#pragma unroll
        for (int t = 0; t < 4; ++t) {
            f32x4 a, c;
#pragma unroll
            for (int r = 0; r < 4; ++r) {
                a[r] = o0[4 * t + r] * linv;
                c[r] = o1[4 * t + r] * linv;
            }
            *reinterpret_cast<f32x4*>(orow + 8 * t + 4 * hi)      = a;
            *reinterpret_cast<f32x4*>(orow + 32 + 8 * t + 4 * hi) = c;
        }
    }
}

extern "C" void kernel_launch(void* const* d_in, const int* in_sizes, int n_in,
                              void* d_out, int out_size, void* d_ws, size_t ws_size,
                              hipStream_t stream) {
    const float* x   = (const float*)d_in[0];
    const float* pos = (const float*)d_in[1];
    const float* Wq  = (const float*)d_in[2];
    const float* Wk  = (const float*)d_in[3];
    float* out = (float*)d_out;

    // ws (bf16 elems): Q 4.19M | K 4.19M | Vt 4.19M  (~25MB)
    unsigned short* Qb  = (unsigned short*)d_ws;
    unsigned short* Kbf = Qb  + 4194304;
    unsigned short* Vtb = Kbf + 4194304;

    xpose_v<<<dim3(8, 8, 4), dim3(256), 0, stream>>>(x, Vtb);
    gemm_qk<<<dim3(64, 8), dim3(256), 0, stream>>>(x, Wq, Wk, Qb, Kbf);
    attn_fwd<<<dim3(1024), dim3(256), 0, stream>>>(Qb, Kbf, Vtb, pos, out);
}

// Round 13
// 155.854 us; speedup vs baseline: 1.1803x; 1.1803x over previous
//
#include <hip/hip_runtime.h>
#include <hip/hip_bf16.h>

typedef __bf16 bf16x8 __attribute__((ext_vector_type(8)));
typedef float f32x4 __attribute__((ext_vector_type(4)));
typedef float f32x16 __attribute__((ext_vector_type(16)));

__device__ inline unsigned short f2bf(float f) {
    __hip_bfloat16 h = __float2bfloat16(f);
    return __builtin_bit_cast(unsigned short, h);
}
__device__ inline unsigned pk2bf(float a, float b) {
    return (unsigned)f2bf(a) | ((unsigned)f2bf(b) << 16);
}
__device__ inline float exp2_fast(float x) {
    float r;
    asm("v_exp_f32 %0, %1" : "=v"(r) : "v"(x));
    return r;
}

#define QSCALE 0.1803368801111244f  /* 0.125 * log2(e) */

// ---------------- V transpose: x[b][n][hc+d] (f32) -> Vt[b*8+h][d][n'] (bf16) --------
// n' = column-permuted n (swap bit2<->bit3 within each 16-block) so the PV MFMA
// fragment's 8 elements are contiguous 16 bytes (single 16B load).
__global__ __launch_bounds__(256) void xpose_v(const float* __restrict__ x,
                                               unsigned short* __restrict__ Vt) {
    const int tid = threadIdx.x;
    const int lane = tid & 63, w = tid >> 6;
    const int b = blockIdx.z, h = blockIdx.y;
    const int n = blockIdx.x * 256 + w * 64 + lane;
    const int np = (n & ~15) | (n & 3) | ((n & 4) << 1) | ((n & 8) >> 1);
    const size_t xrow = ((size_t)b * 2048 + n) * 512 + h * 64;
    const size_t vbase = ((size_t)(b * 8 + h) * 64) * 2048 + np;
#pragma unroll
    for (int d0 = 0; d0 < 64; d0 += 4) {
        float4 v = *reinterpret_cast<const float4*>(&x[xrow + d0]);
        Vt[vbase + (size_t)(d0 + 0) * 2048] = f2bf(v.x);
        Vt[vbase + (size_t)(d0 + 1) * 2048] = f2bf(v.y);
        Vt[vbase + (size_t)(d0 + 2) * 2048] = f2bf(v.z);
        Vt[vbase + (size_t)(d0 + 3) * 2048] = f2bf(v.w);
    }
}

// ---------------- fused Q/K projection: C = x(8192x512) * W^T, f32 in, bf16 out ------
__global__ __launch_bounds__(256) void gemm_qk(const float* __restrict__ x,
                                               const float* __restrict__ Wq,
                                               const float* __restrict__ Wk,
                                               unsigned short* __restrict__ Qb,
                                               unsigned short* __restrict__ Kb) {
    __shared__ __align__(16) unsigned short sA[128 * 40];
    __shared__ __align__(16) unsigned short sB[128 * 40];
    const int tid  = threadIdx.x;
    const int lane = tid & 63;
    const int wave = tid >> 6;
    const int wr = wave >> 1, wc = wave & 1;
    const int bm = blockIdx.x * 128;
    const int by = blockIdx.y;
    const float* __restrict__ Bsrc = (by < 4) ? Wq : Wk;
    unsigned short* __restrict__ C = (by < 4) ? Qb : Kb;
    const int bn = (by & 3) * 128;
    const float scale = (by < 4) ? QSCALE : 1.0f;
    const int tr = tid >> 1, th = (tid & 1) * 16;
    const int rl = lane & 15;
    const int kq = (lane >> 4) * 8;

    f32x4 acc[4][4];
#pragma unroll
    for (int m = 0; m < 4; ++m)
#pragma unroll
        for (int n = 0; n < 4; ++n) acc[m][n] = (f32x4){0.f, 0.f, 0.f, 0.f};

    for (int k0 = 0; k0 < 512; k0 += 32) {
        const float* ap = &x[(size_t)(bm + tr) * 512 + k0 + th];
        const float* bp = &Bsrc[(size_t)(bn + tr) * 512 + k0 + th];
        float4 a0 = *reinterpret_cast<const float4*>(ap);
        float4 a1 = *reinterpret_cast<const float4*>(ap + 4);
        float4 a2 = *reinterpret_cast<const float4*>(ap + 8);
        float4 a3 = *reinterpret_cast<const float4*>(ap + 12);
        float4 b0 = *reinterpret_cast<const float4*>(bp);
        float4 b1 = *reinterpret_cast<const float4*>(bp + 4);
        float4 b2 = *reinterpret_cast<const float4*>(bp + 8);
        float4 b3 = *reinterpret_cast<const float4*>(bp + 12);
        uint4 pa0 = {pk2bf(a0.x, a0.y), pk2bf(a0.z, a0.w), pk2bf(a1.x, a1.y), pk2bf(a1.z, a1.w)};
        uint4 pa1 = {pk2bf(a2.x, a2.y), pk2bf(a2.z, a2.w), pk2bf(a3.x, a3.y), pk2bf(a3.z, a3.w)};
        uint4 pb0 = {pk2bf(b0.x, b0.y), pk2bf(b0.z, b0.w), pk2bf(b1.x, b1.y), pk2bf(b1.z, b1.w)};
        uint4 pb1 = {pk2bf(b2.x, b2.y), pk2bf(b2.z, b2.w), pk2bf(b3.x, b3.y), pk2bf(b3.z, b3.w)};
        __syncthreads();
        *reinterpret_cast<uint4*>(&sA[tr * 40 + th])     = pa0;
        *reinterpret_cast<uint4*>(&sA[tr * 40 + th + 8]) = pa1;
        *reinterpret_cast<uint4*>(&sB[tr * 40 + th])     = pb0;
        *reinterpret_cast<uint4*>(&sB[tr * 40 + th + 8]) = pb1;
        __syncthreads();

        bf16x8 af[4], bfv[4];
#pragma unroll
        for (int m = 0; m < 4; ++m)
            af[m] = __builtin_bit_cast(bf16x8,
                *reinterpret_cast<const uint4*>(&sA[(wr * 64 + m * 16 + rl) * 40 + kq]));
#pragma unroll
        for (int n = 0; n < 4; ++n)
            bfv[n] = __builtin_bit_cast(bf16x8,
                *reinterpret_cast<const uint4*>(&sB[(wc * 64 + n * 16 + rl) * 40 + kq]));
#pragma unroll
        for (int m = 0; m < 4; ++m)
#pragma unroll
            for (int n = 0; n < 4; ++n)
                acc[m][n] = __builtin_amdgcn_mfma_f32_16x16x32_bf16(af[m], bfv[n], acc[m][n], 0, 0, 0);
    }

    const int rq = (lane >> 4) * 4;
#pragma unroll
    for (int m = 0; m < 4; ++m) {
        int r = bm + wr * 64 + m * 16 + rq;
#pragma unroll
        for (int n = 0; n < 4; ++n) {
            int c = bn + wc * 64 + n * 16 + rl;
#pragma unroll
            for (int reg = 0; reg < 4; ++reg)
                C[(size_t)(r + reg) * 512 + c] = f2bf(acc[m][n][reg] * scale);
        }
    }
}

// ---------------- fused flash attention: NO K/V LDS staging (L2-resident K/V) --------
// grid: 1024 flat blocks (XCD bh-affinity: xcd=flat&7 owns bh {4xcd..4xcd+3}).
// block: 256 = 4 waves = 2qh x 2jp; q-tile 64, wave q-sub-tile 32; jp = 32-j parity.
// Per wave: fully independent j-loop, ZERO barriers. K fragments loaded at tile top
// (L1/L2-hit, latency hidden by 4 waves/SIMD); V fragments loaded AFTER the QK MFMAs
// (reuses dead K registers; latency hides under the softmax VALU chain). No register
// prefetch (round-12 spill fix: peak live ~90 VGPR < 128 cap).
// Fragment maps identical to verified round-9/12 kernels:
//   S^T = mfma(K,Q): lane q=l31, j=(r&3)+8*(r>>2)+4*hi; operand elem c=16ks+8hi+e.
//   PV = mfma(V',P): P lane-local j-map 16ks+4hi+(e&3)+8*(e>>2); V' pre-permuted.
__global__ __launch_bounds__(256, 4) void attn_fwd(const unsigned short* __restrict__ Q,
                                                   const unsigned short* __restrict__ Kb,
                                                   const unsigned short* __restrict__ Vt,
                                                   const float* __restrict__ pos,
                                                   float* __restrict__ Out) {
    __shared__ __align__(16) unsigned char smem[16896];
    float* sPos = (float*)smem;   // loop phase: 2048 f32 (slopeL*pos); epilogue aliases

    const int tid  = threadIdx.x;
    const int lane = tid & 63;
    const int w    = tid >> 6;
    const int l31  = lane & 31;
    const int hi   = lane >> 5;
    const int qh   = w & 1;
    const int jp   = w >> 1;
    const int flat = blockIdx.x;
    const int xcd  = flat & 7;
    const int idx  = flat >> 3;          // 0..127
    const int bh   = xcd * 4 + (idx >> 5);
    const int qt   = idx & 31;
    const int b = bh >> 3, h = bh & 7;
    const int q0 = qt * 64 + qh * 32;
    const size_t rowbase = (size_t)b * 2048;
    const int hc = h * 64;
    const float slopeL = ldexpf(1.4426950408889634f, -(h + 1));  // slope * log2(e)

    // Q B-fragments (Q pre-scaled by 0.125*log2e)
    bf16x8 qf0, qf1, qf2, qf3;
    {
        const unsigned short* qp = &Q[(rowbase + q0 + l31) * 512 + hc + hi * 8];
        qf0 = __builtin_bit_cast(bf16x8, *reinterpret_cast<const uint4*>(qp));
        qf1 = __builtin_bit_cast(bf16x8, *reinterpret_cast<const uint4*>(qp + 16));
        qf2 = __builtin_bit_cast(bf16x8, *reinterpret_cast<const uint4*>(qp + 32));
        qf3 = __builtin_bit_cast(bf16x8, *reinterpret_cast<const uint4*>(qp + 48));
    }
    const float ui = slopeL * pos[rowbase + q0 + l31];

    // slopeL*pos table (one-time, vectorized)
    {
        f32x4* sp4 = (f32x4*)sPos;
        const float4* gp4 = (const float4*)(pos + rowbase);
#pragma unroll
        for (int i = 0; i < 2; ++i) {
            float4 v = gp4[tid + 256 * i];
            sp4[tid + 256 * i] = (f32x4){v.x * slopeL, v.y * slopeL, v.z * slopeL, v.w * slopeL};
        }
    }
    __syncthreads();

    float lloc = 0.f;
    f32x16 o0, o1;
#pragma unroll
    for (int r = 0; r < 16; ++r) { o0[r] = 0.f; o1[r] = 0.f; }

    // direct-global fragment bases
    const unsigned short* Kbase  = &Kb[(rowbase + 32 * jp + l31) * 512 + hc + hi * 8];
    const unsigned short* Vbase0 = &Vt[((size_t)bh * 64 + l31) * 2048 + 32 * jp + 8 * hi];
    const unsigned short* Vbase1 = Vbase0 + (size_t)32 * 2048;

    for (int t = 0; t < 32; ++t) {
        const int j0 = 64 * t + 32 * jp;
        // ---- K fragment loads (L1/L2 hit; no prefetch, no extra live set) ----
        const unsigned short* kp = Kbase + (size_t)t * 64 * 512;
        uint4 k0 = *reinterpret_cast<const uint4*>(kp);
        uint4 k1 = *reinterpret_cast<const uint4*>(kp + 16);
        uint4 k2 = *reinterpret_cast<const uint4*>(kp + 32);
        uint4 k3 = *reinterpret_cast<const uint4*>(kp + 48);

        // ---- S chunk (32j x 32q) ----
        f32x16 s;
#pragma unroll
        for (int r = 0; r < 16; ++r) s[r] = 0.f;
        __builtin_amdgcn_s_setprio(1);
        s = __builtin_amdgcn_mfma_f32_32x32x16_bf16(__builtin_bit_cast(bf16x8, k0), qf0, s, 0, 0, 0);
        s = __builtin_amdgcn_mfma_f32_32x32x16_bf16(__builtin_bit_cast(bf16x8, k1), qf1, s, 0, 0, 0);
        s = __builtin_amdgcn_mfma_f32_32x32x16_bf16(__builtin_bit_cast(bf16x8, k2), qf2, s, 0, 0, 0);
        s = __builtin_amdgcn_mfma_f32_32x32x16_bf16(__builtin_bit_cast(bf16x8, k3), qf3, s, 0, 0, 0);
        __builtin_amdgcn_s_setprio(0);

        // ---- V fragment loads (K regs now dead -> reuse; latency hides under softmax)
        const unsigned short* vp0 = Vbase0 + t * 64;
        const unsigned short* vp1 = Vbase1 + t * 64;
        uint4 v00 = *reinterpret_cast<const uint4*>(vp0);
        uint4 v01 = *reinterpret_cast<const uint4*>(vp0 + 16);
        uint4 v10 = *reinterpret_cast<const uint4*>(vp1);
        uint4 v11 = *reinterpret_cast<const uint4*>(vp1 + 16);

        // ---- bias + exp2 (fixed reference, log2 domain) ----
        float ls = 0.f;
#pragma unroll
        for (int tt = 0; tt < 4; ++tt) {
            f32x4 u = *reinterpret_cast<const f32x4*>(&sPos[j0 + 8 * tt + 4 * hi]);
#pragma unroll
            for (int r = 0; r < 4; ++r) {
                float p = exp2_fast(s[4 * tt + r] - fabsf(u[r] - ui));
                s[4 * tt + r] = p;
                ls += p;
            }
        }
        lloc += ls;

        // ---- lane-local P fragments (j = 16ks + 4hi + (e&3) + 8*(e>>2)) ----
        bf16x8 pf0 = __builtin_bit_cast(bf16x8, (uint4){
            pk2bf(s[0], s[1]),  pk2bf(s[2], s[3]),   pk2bf(s[4], s[5]),   pk2bf(s[6], s[7])});
        bf16x8 pf1 = __builtin_bit_cast(bf16x8, (uint4){
            pk2bf(s[8], s[9]),  pk2bf(s[10], s[11]), pk2bf(s[12], s[13]), pk2bf(s[14], s[15])});

        // ---- PV: O^T[d][q] += V-frag x P-frag ----
        __builtin_amdgcn_s_setprio(1);
        o0 = __builtin_amdgcn_mfma_f32_32x32x16_bf16(__builtin_bit_cast(bf16x8, v00), pf0, o0, 0, 0, 0);
        o1 = __builtin_amdgcn_mfma_f32_32x32x16_bf16(__builtin_bit_cast(bf16x8, v10), pf0, o1, 0, 0, 0);
        o0 = __builtin_amdgcn_mfma_f32_32x32x16_bf16(__builtin_bit_cast(bf16x8, v01), pf1, o0, 0, 0, 0);
        o1 = __builtin_amdgcn_mfma_f32_32x32x16_bf16(__builtin_bit_cast(bf16x8, v11), pf1, o1, 0, 0, 0);
        __builtin_amdgcn_s_setprio(0);
    }

    // ---- epilogue: merge jp partials via LDS (aliases sPos), normalize, store ----
    float lt = lloc + __shfl_xor(lloc, 32, 64);  // combine hi halves (same q)
    __syncthreads();                             // everyone done with loop & sPos
    float* sMf = (float*)smem;                   // 2 qh x 32 q x 64 d = 16 KiB
    float* sMl = sMf + 4096;                     // 128 f32
    const int key = (lane & 7) << 2;
    if (jp == 1) {
        float* dst = sMf + qh * 2048 + lane * 32;
#pragma unroll
        for (int i = 0; i < 4; ++i) {
            f32x4 t0 = {o0[4 * i], o0[4 * i + 1], o0[4 * i + 2], o0[4 * i + 3]};
            f32x4 t1 = {o1[4 * i], o1[4 * i + 1], o1[4 * i + 2], o1[4 * i + 3]};
            *reinterpret_cast<f32x4*>(dst + ((4 * i) ^ key))      = t0;
            *reinterpret_cast<f32x4*>(dst + ((16 + 4 * i) ^ key)) = t1;
        }
        sMl[qh * 64 + lane] = lt;
    }
    __syncthreads();
    if (jp == 0) {
        const float* src = sMf + qh * 2048 + lane * 32;
#pragma unroll
        for (int i = 0; i < 4; ++i) {
            f32x4 t0 = *reinterpret_cast<const f32x4*>(src + ((4 * i) ^ key));
            f32x4 t1 = *reinterpret_cast<const f32x4*>(src + ((16 + 4 * i) ^ key));
#pragma unroll
            for (int r = 0; r < 4; ++r) { o0[4 * i + r] += t0[r]; o1[4 * i + r] += t1[r]; }
        }
        const float linv = 1.0f / (lt + sMl[qh * 64 + lane]);
        float* orow = &Out[(rowbase + q0 + l31) * 512 + hc];
#pragma unroll
        for (int t = 0; t < 4; ++t) {
            f32x4 a, c;
#pragma unroll
            for (int r = 0; r < 4; ++r) {
                a[r] = o0[4 * t + r] * linv;
                c[r] = o1[4 * t + r] * linv;
            }
            *reinterpret_cast<f32x4*>(orow + 8 * t + 4 * hi)      = a;
            *reinterpret_cast<f32x4*>(orow + 32 + 8 * t + 4 * hi) = c;
        }
    }
}

extern "C" void kernel_launch(void* const* d_in, const int* in_sizes, int n_in,
                              void* d_out, int out_size, void* d_ws, size_t ws_size,
                              hipStream_t stream) {
    const float* x   = (const float*)d_in[0];
    const float* pos = (const float*)d_in[1];
    const float* Wq  = (const float*)d_in[2];
    const float* Wk  = (const float*)d_in[3];
    float* out = (float*)d_out;

    // ws (bf16 elems): Q 4.19M | K 4.19M | Vt 4.19M  (~25MB)
    unsigned short* Qb  = (unsigned short*)d_ws;
    unsigned short* Kbf = Qb  + 4194304;
    unsigned short* Vtb = Kbf + 4194304;

    xpose_v<<<dim3(8, 8, 4), dim3(256), 0, stream>>>(x, Vtb);
    gemm_qk<<<dim3(64, 8), dim3(256), 0, stream>>>(x, Wq, Wk, Qb, Kbf);
    attn_fwd<<<dim3(1024), dim3(256), 0, stream>>>(Qb, Kbf, Vtb, pos, out);
}

// Round 14
// 79.695 us; speedup vs baseline: 2.3083x; 1.9556x over previous
//
#include <hip/hip_runtime.h>
#include <hip/hip_bf16.h>

typedef __bf16 bf16x8 __attribute__((ext_vector_type(8)));
typedef float f32x4 __attribute__((ext_vector_type(4)));
typedef float f32x16 __attribute__((ext_vector_type(16)));

__device__ inline unsigned short f2bf(float f) {
    __hip_bfloat16 h = __float2bfloat16(f);
    return __builtin_bit_cast(unsigned short, h);
}
__device__ inline unsigned pk2bf(float a, float b) {
    return (unsigned)f2bf(a) | ((unsigned)f2bf(b) << 16);
}
__device__ inline float exp2_fast(float x) {
    float r;
    asm("v_exp_f32 %0, %1" : "=v"(r) : "v"(x));
    return r;
}

#define QSCALE 0.1803368801111244f  /* 0.125 * log2(e) */

// ------- fused projection + V-transpose: grid (64, 12) x 256 threads -----------------
// by 0..3:  Q = (x Wq^T) * QSCALE   (128x128 GEMM tile)
// by 4..7:  K = x Wk^T
// by 8..11: V transpose slice: x[b][n][hc+d] -> Vt[b*8+h][d][n'] for h = 2(by-8)+{0,1},
//           rows g in [bx*128, bx*128+128). n' = bit2<->bit3 permuted within 16-block
//           (makes the PV MFMA fragment contiguous 16B). Mem-bound slice co-schedules
//           with the MFMA-bound GEMM blocks.
__global__ __launch_bounds__(256) void gemm_qk(const float* __restrict__ x,
                                               const float* __restrict__ Wq,
                                               const float* __restrict__ Wk,
                                               unsigned short* __restrict__ Qb,
                                               unsigned short* __restrict__ Kb,
                                               unsigned short* __restrict__ Vt) {
    __shared__ __align__(16) unsigned short sA[128 * 40];
    __shared__ __align__(16) unsigned short sB[128 * 40];
    const int tid  = threadIdx.x;
    const int by = blockIdx.y;

    if (by >= 8) {  // ---- V transpose slice ----
        const int q = by - 8;
        const int nl = tid & 127, hh = tid >> 7;
        const int h = q * 2 + hh;
        const int g = blockIdx.x * 128 + nl;       // global row 0..8191
        const int b = g >> 11, n = g & 2047;
        const int np = (n & ~15) | (n & 3) | ((n & 4) << 1) | ((n & 8) >> 1);
        const size_t xrow = ((size_t)b * 2048 + n) * 512 + h * 64;
        const size_t vbase = ((size_t)(b * 8 + h) * 64) * 2048 + np;
#pragma unroll
        for (int d0 = 0; d0 < 64; d0 += 4) {
            float4 v = *reinterpret_cast<const float4*>(&x[xrow + d0]);
            Vt[vbase + (size_t)(d0 + 0) * 2048] = f2bf(v.x);
            Vt[vbase + (size_t)(d0 + 1) * 2048] = f2bf(v.y);
            Vt[vbase + (size_t)(d0 + 2) * 2048] = f2bf(v.z);
            Vt[vbase + (size_t)(d0 + 3) * 2048] = f2bf(v.w);
        }
        return;
    }

    const int lane = tid & 63;
    const int wave = tid >> 6;
    const int wr = wave >> 1, wc = wave & 1;
    const int bm = blockIdx.x * 128;
    const float* __restrict__ Bsrc = (by < 4) ? Wq : Wk;
    unsigned short* __restrict__ C = (by < 4) ? Qb : Kb;
    const int bn = (by & 3) * 128;
    const float scale = (by < 4) ? QSCALE : 1.0f;
    const int tr = tid >> 1, th = (tid & 1) * 16;
    const int rl = lane & 15;
    const int kq = (lane >> 4) * 8;

    f32x4 acc[4][4];
#pragma unroll
    for (int m = 0; m < 4; ++m)
#pragma unroll
        for (int n = 0; n < 4; ++n) acc[m][n] = (f32x4){0.f, 0.f, 0.f, 0.f};

    for (int k0 = 0; k0 < 512; k0 += 32) {
        const float* ap = &x[(size_t)(bm + tr) * 512 + k0 + th];
        const float* bp = &Bsrc[(size_t)(bn + tr) * 512 + k0 + th];
        float4 a0 = *reinterpret_cast<const float4*>(ap);
        float4 a1 = *reinterpret_cast<const float4*>(ap + 4);
        float4 a2 = *reinterpret_cast<const float4*>(ap + 8);
        float4 a3 = *reinterpret_cast<const float4*>(ap + 12);
        float4 b0 = *reinterpret_cast<const float4*>(bp);
        float4 b1 = *reinterpret_cast<const float4*>(bp + 4);
        float4 b2 = *reinterpret_cast<const float4*>(bp + 8);
        float4 b3 = *reinterpret_cast<const float4*>(bp + 12);
        uint4 pa0 = {pk2bf(a0.x, a0.y), pk2bf(a0.z, a0.w), pk2bf(a1.x, a1.y), pk2bf(a1.z, a1.w)};
        uint4 pa1 = {pk2bf(a2.x, a2.y), pk2bf(a2.z, a2.w), pk2bf(a3.x, a3.y), pk2bf(a3.z, a3.w)};
        uint4 pb0 = {pk2bf(b0.x, b0.y), pk2bf(b0.z, b0.w), pk2bf(b1.x, b1.y), pk2bf(b1.z, b1.w)};
        uint4 pb1 = {pk2bf(b2.x, b2.y), pk2bf(b2.z, b2.w), pk2bf(b3.x, b3.y), pk2bf(b3.z, b3.w)};
        __syncthreads();
        *reinterpret_cast<uint4*>(&sA[tr * 40 + th])     = pa0;
        *reinterpret_cast<uint4*>(&sA[tr * 40 + th + 8]) = pa1;
        *reinterpret_cast<uint4*>(&sB[tr * 40 + th])     = pb0;
        *reinterpret_cast<uint4*>(&sB[tr * 40 + th + 8]) = pb1;
        __syncthreads();

        bf16x8 af[4], bfv[4];
#pragma unroll
        for (int m = 0; m < 4; ++m)
            af[m] = __builtin_bit_cast(bf16x8,
                *reinterpret_cast<const uint4*>(&sA[(wr * 64 + m * 16 + rl) * 40 + kq]));
#pragma unroll
        for (int n = 0; n < 4; ++n)
            bfv[n] = __builtin_bit_cast(bf16x8,
                *reinterpret_cast<const uint4*>(&sB[(wc * 64 + n * 16 + rl) * 40 + kq]));
#pragma unroll
        for (int m = 0; m < 4; ++m)
#pragma unroll
            for (int n = 0; n < 4; ++n)
                acc[m][n] = __builtin_amdgcn_mfma_f32_16x16x32_bf16(af[m], bfv[n], acc[m][n], 0, 0, 0);
    }

    const int rq = (lane >> 4) * 4;
#pragma unroll
    for (int m = 0; m < 4; ++m) {
        int r = bm + wr * 64 + m * 16 + rq;
#pragma unroll
        for (int n = 0; n < 4; ++n) {
            int c = bn + wc * 64 + n * 16 + rl;
#pragma unroll
            for (int reg = 0; reg < 4; ++reg)
                C[(size_t)(r + reg) * 512 + c] = f2bf(acc[m][n][reg] * scale);
        }
    }
}

// ---------------- fused flash attention: 8 waves (4qh x 2jp), dbuf, 1 barrier/tile ---
// grid: 512 flat blocks, XCD bh-affinity (xcd=flat&7 owns bh {4xcd..4xcd+3}) -> per-XCD
// K/V working set 2MB, L2-resident (round-11 verified: FETCH 5x down).
// block: 512 = 8 waves; wave w: qh=w&3 (32 q of the 128-q tile), jp=w>>2 (32-j chunk).
// Fixed-reference softmax in log2 domain (log2e folded into Q-scale and slope).
// One-time sPos table (slopeL*pos, 8KB LDS) removes pos staging from the loop.
// S^T: mfma(K,Q) -> D[row=j][col=q]: lane q=l31, j=(r&3)+8*(r>>2)+4*hi.
// PV: P-frag lane-local, j-map = 16ks + 4hi + (e&3) + 8*(e>>2); V pre-permuted so this
// fragment is one contiguous b128 read. LDS rows XOR-swizzled (byte ^= (row&7)<<4).
__global__ __launch_bounds__(512, 4) void attn_fwd(const unsigned short* __restrict__ Q,
                                                   const unsigned short* __restrict__ Kb,
                                                   const unsigned short* __restrict__ Vt,
                                                   const float* __restrict__ pos,
                                                   float* __restrict__ Out) {
    __shared__ __align__(16) unsigned char smem[42240];
    char* k0b = (char*)smem;                 // 8 KiB
    char* v0b = (char*)smem + 8192;          // 8 KiB
    char* k1b = (char*)smem + 16384;         // 8 KiB
    char* v1b = (char*)smem + 24576;         // 8 KiB
    float* sPosT = (float*)(smem + 32768);   // 2048 f32 slopeL*pos (8 KiB)
    float* sMl   = (float*)(smem + 40960);   // 256 f32 (epilogue l merge)

    const int tid  = threadIdx.x;
    const int lane = tid & 63;
    const int w    = tid >> 6;
    const int l31  = lane & 31;
    const int hi   = lane >> 5;
    const int qh   = w & 3;
    const int jp   = w >> 2;
    // XCD-affine decode (512 blocks, bijective: 512 % 8 == 0)
    const int flat = blockIdx.x;
    const int xcd  = flat & 7;
    const int idx  = flat >> 3;              // 0..63
    const int bh   = xcd * 4 + (idx >> 4);
    const int qt   = idx & 15;
    const int b = bh >> 3, h = bh & 7;
    const int q0 = qt * 128 + qh * 32;
    const size_t rowbase = (size_t)b * 2048;
    const int hc = h * 64;
    const float slopeL = ldexpf(1.4426950408889634f, -(h + 1));  // slope * log2(e)

    // Q B-fragments: lane supplies Q[q=l31][c = ks*16 + hi*8 + e] (Q pre-scaled)
    bf16x8 qf0, qf1, qf2, qf3;
    {
        const unsigned short* qp = &Q[(rowbase + q0 + l31) * 512 + hc + hi * 8];
        qf0 = __builtin_bit_cast(bf16x8, *reinterpret_cast<const uint4*>(qp));
        qf1 = __builtin_bit_cast(bf16x8, *reinterpret_cast<const uint4*>(qp + 16));
        qf2 = __builtin_bit_cast(bf16x8, *reinterpret_cast<const uint4*>(qp + 32));
        qf3 = __builtin_bit_cast(bf16x8, *reinterpret_cast<const uint4*>(qp + 48));
    }
    const float ui = slopeL * pos[rowbase + q0 + l31];

    // one-time slopeL*pos table (512 threads x 4 = 2048)
    {
        float4 v = reinterpret_cast<const float4*>(pos + rowbase)[tid];
        reinterpret_cast<f32x4*>(sPosT)[tid] =
            (f32x4){v.x * slopeL, v.y * slopeL, v.z * slopeL, v.w * slopeL};
    }

    float lloc = 0.f;
    f32x16 o0, o1;
#pragma unroll
    for (int r = 0; r < 16; ++r) { o0[r] = 0.f; o1[r] = 0.f; }

    // staging: 8 threads/row x 16 B; write slot XOR-swizzled -> conflict-free
    const int sr  = tid >> 3;                       // row 0..63
    const int sce = (tid & 7) * 8;                  // elem col (8 elems/thread)
    const int wbyte = sr * 128 + (((tid & 7) * 16) ^ ((sr & 7) << 4));
    const int kswz = (l31 & 7) << 4;                // compute-side swizzle key

    uint4 ck, cv;

    auto stage = [&](int j0v) {
        ck = *reinterpret_cast<const uint4*>(&Kb[(rowbase + j0v + sr) * 512 + hc + sce]);
        cv = *reinterpret_cast<const uint4*>(&Vt[((size_t)bh * 64 + sr) * 2048 + j0v + sce]);
    };
    auto writeb = [&](char* KB, char* VB) {
        *reinterpret_cast<uint4*>(KB + wbyte) = ck;
        *reinterpret_cast<uint4*>(VB + wbyte) = cv;
    };
    auto compute = [&](const char* KB, const char* VB, int j0) {
        const char* kr = KB + (32 * jp + l31) * 128;
        // ---- S chunk (32j x 32q) for this wave's (qh, jp) ----
        f32x16 s;
#pragma unroll
        for (int r = 0; r < 16; ++r) s[r] = 0.f;
        __builtin_amdgcn_s_setprio(1);
#pragma unroll
        for (int ks = 0; ks < 4; ++ks) {
            bf16x8 kf = __builtin_bit_cast(bf16x8,
                *reinterpret_cast<const uint4*>(kr + ((ks * 32 + hi * 16) ^ kswz)));
            bf16x8 qq = (ks == 0) ? qf0 : (ks == 1) ? qf1 : (ks == 2) ? qf2 : qf3;
            s = __builtin_amdgcn_mfma_f32_32x32x16_bf16(kf, qq, s, 0, 0, 0);
        }
        __builtin_amdgcn_s_setprio(0);

        // ---- bias + exp2 (fixed reference, log2 domain) ----
        float ls = 0.f;
#pragma unroll
        for (int t = 0; t < 4; ++t) {
            f32x4 u = *reinterpret_cast<const f32x4*>(&sPosT[j0 + 32 * jp + 8 * t + 4 * hi]);
#pragma unroll
            for (int r = 0; r < 4; ++r) {
                float p = exp2_fast(s[4 * t + r] - fabsf(u[r] - ui));
                s[4 * t + r] = p;
                ls += p;
            }
        }
        lloc += ls;

        // ---- lane-local P fragments (j = 16ks + 4hi + (e&3) + 8*(e>>2)) ----
        bf16x8 pf0 = __builtin_bit_cast(bf16x8, (uint4){
            pk2bf(s[0], s[1]),  pk2bf(s[2], s[3]),   pk2bf(s[4], s[5]),   pk2bf(s[6], s[7])});
        bf16x8 pf1 = __builtin_bit_cast(bf16x8, (uint4){
            pk2bf(s[8], s[9]),  pk2bf(s[10], s[11]), pk2bf(s[12], s[13]), pk2bf(s[14], s[15])});

        // ---- PV: O^T[d][q] += V-frag x P-frag; V pre-permuted -> single b128/frag ----
        const char* vr0 = VB + l31 * 128;
        const char* vr1 = VB + (32 + l31) * 128;
        __builtin_amdgcn_s_setprio(1);
#pragma unroll
        for (int ks = 0; ks < 2; ++ks) {
            const int cb = (64 * jp + ks * 32 + hi * 16) ^ kswz;  // permuted-stored
            bf16x8 v0 = __builtin_bit_cast(bf16x8, *reinterpret_cast<const uint4*>(vr0 + cb));
            bf16x8 v1 = __builtin_bit_cast(bf16x8, *reinterpret_cast<const uint4*>(vr1 + cb));
            bf16x8 pf = ks ? pf1 : pf0;
            o0 = __builtin_amdgcn_mfma_f32_32x32x16_bf16(v0, pf, o0, 0, 0, 0);
            o1 = __builtin_amdgcn_mfma_f32_32x32x16_bf16(v1, pf, o1, 0, 0, 0);
        }
        __builtin_amdgcn_s_setprio(0);
    };

    // prologue: tile 0 -> buf0; tile 1 -> regs
    stage(0);
    writeb(k0b, v0b);
    stage(64);
    __syncthreads();

    for (int t = 0; t < 32; t += 2) {
        // even iter: compute buf0, regs hold tile t+1 -> buf1
        writeb(k1b, v1b);
        if (t + 2 < 32) stage((t + 2) * 64);
        compute(k0b, v0b, t * 64);
        __syncthreads();
        // odd iter: compute buf1, regs hold tile t+2 -> buf0
        if (t + 2 < 32) {
            writeb(k0b, v0b);
            if (t + 3 < 32) stage((t + 3) * 64);
        }
        compute(k1b, v1b, (t + 1) * 64);
        __syncthreads();
    }

    // ---- epilogue: merge jp partials via LDS, normalize, direct 16B stores ----
    float lt = lloc + __shfl_xor(lloc, 32, 64);  // combine hi halves (same q)
    float* sM = (float*)smem;                    // aliases KV buffers (loop done)
    const int key = (lane & 7) << 2;
    if (jp == 1) {
        float* dst = sM + qh * 2048 + lane * 32;
#pragma unroll
        for (int i = 0; i < 4; ++i) {
            f32x4 t0 = {o0[4 * i], o0[4 * i + 1], o0[4 * i + 2], o0[4 * i + 3]};
            f32x4 t1 = {o1[4 * i], o1[4 * i + 1], o1[4 * i + 2], o1[4 * i + 3]};
            *reinterpret_cast<f32x4*>(dst + ((4 * i) ^ key))      = t0;
            *reinterpret_cast<f32x4*>(dst + ((16 + 4 * i) ^ key)) = t1;
        }
        sMl[qh * 64 + lane] = lt;
    }
    __syncthreads();
    if (jp == 0) {
        const float* src = sM + qh * 2048 + lane * 32;
#pragma unroll
        for (int i = 0; i < 4; ++i) {
            f32x4 t0 = *reinterpret_cast<const f32x4*>(src + ((4 * i) ^ key));
            f32x4 t1 = *reinterpret_cast<const f32x4*>(src + ((16 + 4 * i) ^ key));
#pragma unroll
            for (int r = 0; r < 4; ++r) { o0[4 * i + r] += t0[r]; o1[4 * i + r] += t1[r]; }
        }
        const float linv = 1.0f / (lt + sMl[qh * 64 + lane]);
        float* orow = &Out[(rowbase + q0 + l31) * 512 + hc];
#pragma unroll
        for (int t = 0; t < 4; ++t) {
            f32x4 a, c;
#pragma unroll
            for (int r = 0; r < 4; ++r) {
                a[r] = o0[4 * t + r] * linv;
                c[r] = o1[4 * t + r] * linv;
            }
            *reinterpret_cast<f32x4*>(orow + 8 * t + 4 * hi)      = a;
            *reinterpret_cast<f32x4*>(orow + 32 + 8 * t + 4 * hi) = c;
        }
    }
}

extern "C" void kernel_launch(void* const* d_in, const int* in_sizes, int n_in,
                              void* d_out, int out_size, void* d_ws, size_t ws_size,
                              hipStream_t stream) {
    const float* x   = (const float*)d_in[0];
    const float* pos = (const float*)d_in[1];
    const float* Wq  = (const float*)d_in[2];
    const float* Wk  = (const float*)d_in[3];
    float* out = (float*)d_out;

    // ws (bf16 elems): Q 4.19M | K 4.19M | Vt 4.19M  (~25MB)
    unsigned short* Qb  = (unsigned short*)d_ws;
    unsigned short* Kbf = Qb  + 4194304;
    unsigned short* Vtb = Kbf + 4194304;

    gemm_qk<<<dim3(64, 12), dim3(256), 0, stream>>>(x, Wq, Wk, Qb, Kbf, Vtb);
    attn_fwd<<<dim3(512), dim3(512), 0, stream>>>(Qb, Kbf, Vtb, pos, out);
}